// Round 1
// baseline (27.748 us; speedup 1.0000x reference)
//
#include <hip/hip_runtime.h>
#include <math.h>

#define N_SIZE 4096
#define B_SIZE 8192
#define T_PER_WAVE 4

// tanh(x) = 1 - 2/(exp(2x)+1), exp(2x) = 2^(2x*log2(e))
__device__ __forceinline__ float fast_tanh(float x) {
    float xe = fminf(x * 2.885390081777927f, 80.0f);   // 2*log2(e)
    float e  = __builtin_amdgcn_exp2f(xe);             // v_exp_f32
    return 1.0f - 2.0f * __builtin_amdgcn_rcpf(e + 1.0f);
}

__device__ __forceinline__ float wave_sum(float v) {
#pragma unroll
    for (int off = 32; off >= 1; off >>= 1)
        v += __shfl_xor(v, off, 64);
    return v;
}

__global__ __launch_bounds__(256)
void bif_kernel(const float* __restrict__ k_t,
                const float* __restrict__ phase,
                const float* __restrict__ mono,
                const float* __restrict__ dKn,
                const float* __restrict__ amp_p,
                const float* __restrict__ w_p,
                const float* __restrict__ stim,
                const float* __restrict__ alpha,
                const float* __restrict__ Im,
                const float* __restrict__ mm,
                const float* __restrict__ nm,
                float* __restrict__ out) {
    const int lane = threadIdx.x & 63;
    const int wave = (blockIdx.x * 256 + threadIdx.x) >> 6;
    const int b0   = wave * T_PER_WAVE;

    const float amp = amp_p[0];
    const float w   = w_p[0];
    const float st0 = stim[0];
    const float st1 = stim[1];
    const float tau_sw = w * 0.1f;
    const float phi0 = atanf(tau_sw);                 // atan2(tau_sw, 1)
    const float vamp = amp / sqrtf(1.0f + tau_sw * tau_sw);

    float k0[T_PER_WAVE], k1[T_PER_WAVE], vo[T_PER_WAVE], uo[T_PER_WAVE], ph[T_PER_WAVE];
#pragma unroll
    for (int t = 0; t < T_PER_WAVE; ++t) {
        int b = b0 + t;
        k0[t] = k_t[2 * b];
        k1[t] = k_t[2 * b + 1];
        float p = phase[b];
        ph[t] = p;
        vo[t] = vamp * sinf(p - phi0);
        uo[t] = amp * sinf(p);
    }

    float acc_s0[T_PER_WAVE] = {}, acc_s1[T_PER_WAVE] = {};
    float acc00[T_PER_WAVE] = {}, acc01[T_PER_WAVE] = {};
    float acc10[T_PER_WAVE] = {}, acc11[T_PER_WAVE] = {};

    for (int it = 0; it < N_SIZE / 256; ++it) {       // 16 iterations
        const int j = it * 1024 + lane * 4;
        float4 vm0 = *(const float4*)(mm + j);
        float4 vm1 = *(const float4*)(mm + N_SIZE + j);
        float4 vn0 = *(const float4*)(nm + j);
        float4 vn1 = *(const float4*)(nm + N_SIZE + j);
        float4 vi0 = *(const float4*)(Im + j);
        float4 vi1 = *(const float4*)(Im + N_SIZE + j);
        float4 vi2 = *(const float4*)(Im + 2 * N_SIZE + j);
        const float* pm0 = (const float*)&vm0;
        const float* pm1 = (const float*)&vm1;
        const float* pn0 = (const float*)&vn0;
        const float* pn1 = (const float*)&vn1;
        const float* pi0 = (const float*)&vi0;
        const float* pi1 = (const float*)&vi1;
        const float* pi2 = (const float*)&vi2;
#pragma unroll
        for (int e = 0; e < 4; ++e) {
            const float M0 = pm0[e], M1 = pm1[e];
            const float Nv0 = pn0[e], Nv1 = pn1[e];
            const float I0 = pi0[e];
            const float cv = fmaf(st0, pi1[e], st1 * pi2[e]);  // stim part of v@I
#pragma unroll
            for (int t = 0; t < T_PER_WAVE; ++t) {
                float x  = fmaf(k0[t], M0, fmaf(k1[t], M1, fmaf(vo[t], I0, cv)));
                float tx = fast_tanh(x);
                acc_s0[t] = fmaf(tx, Nv0, acc_s0[t]);
                acc_s1[t] = fmaf(tx, Nv1, acc_s1[t]);
                float dphi = fmaf(-tx, tx, 1.0f);
                float a0 = dphi * M0;
                float a1 = dphi * M1;
                acc00[t] = fmaf(a0, Nv0, acc00[t]);
                acc01[t] = fmaf(a0, Nv1, acc01[t]);
                acc10[t] = fmaf(a1, Nv0, acc10[t]);
                acc11[t] = fmaf(a1, Nv1, acc11[t]);
            }
        }
    }

#pragma unroll
    for (int t = 0; t < T_PER_WAVE; ++t) {
        acc_s0[t] = wave_sum(acc_s0[t]);
        acc_s1[t] = wave_sum(acc_s1[t]);
        acc00[t]  = wave_sum(acc00[t]);
        acc01[t]  = wave_sum(acc01[t]);
        acc10[t]  = wave_sum(acc10[t]);
        acc11[t]  = wave_sum(acc11[t]);
    }

    if (lane == 0) {
        const float a00 = alpha[0], a01 = alpha[1], a02 = alpha[2];
        const float a10 = alpha[3], a11 = alpha[4], a12 = alpha[5];
        const float invN = 1.0f / 4096.0f;
        const float DT = 0.0005f;
#pragma unroll
        for (int t = 0; t < T_PER_WAVE; ++t) {
            const int b = b0 + t;
            float ua0 = uo[t] * a00 + st0 * a01 + st1 * a02;
            float ua1 = uo[t] * a10 + st0 * a11 + st1 * a12;
            float dK0 = 10.0f * (-k0[t] + acc_s0[t] * invN + ua0);
            float dK1 = 10.0f * (-k1[t] + acc_s1[t] * invN + ua1);
            out[2 * b]     = fmaf(DT, dK0, k0[t]);
            out[2 * b + 1] = fmaf(DT, dK1, k1[t]);
            out[B_SIZE * 2 + b] = ph[t] + DT * w;
            float J00 = 10.0f * (acc00[t] * invN - 1.0f);
            float J01 = 10.0f * (acc01[t] * invN);
            float J10 = 10.0f * (acc10[t] * invN);
            float J11 = 10.0f * (acc11[t] * invN - 1.0f);
            float M00 = mono[4 * b], M01 = mono[4 * b + 1];
            float M10 = mono[4 * b + 2], M11 = mono[4 * b + 3];
            float* om = out + B_SIZE * 3 + 4 * b;
            om[0] = M00 + DT * (J00 * M00 + J01 * M10);
            om[1] = M01 + DT * (J00 * M01 + J01 * M11);
            om[2] = M10 + DT * (J10 * M00 + J11 * M10);
            om[3] = M11 + DT * (J10 * M01 + J11 * M11);
            out[B_SIZE * 7 + b] = dKn[b] + sqrtf(dK0 * dK0 + dK1 * dK1);
        }
    }
}

extern "C" void kernel_launch(void* const* d_in, const int* in_sizes, int n_in,
                              void* d_out, int out_size, void* d_ws, size_t ws_size,
                              hipStream_t stream) {
    const float* k_t   = (const float*)d_in[0];
    const float* phase = (const float*)d_in[1];
    const float* mono  = (const float*)d_in[2];
    const float* dKn   = (const float*)d_in[3];
    const float* amp   = (const float*)d_in[4];
    const float* w     = (const float*)d_in[5];
    const float* stim  = (const float*)d_in[6];
    const float* alpha = (const float*)d_in[7];
    const float* Im    = (const float*)d_in[8];
    const float* mm    = (const float*)d_in[9];
    const float* nm    = (const float*)d_in[10];
    float* out = (float*)d_out;

    // 8192 trials / 4 trials-per-wave = 2048 waves; 4 waves (256 thr) per block
    const int blocks = B_SIZE / (T_PER_WAVE * 4);
    bif_kernel<<<blocks, 256, 0, stream>>>(k_t, phase, mono, dKn, amp, w,
                                           stim, alpha, Im, mm, nm, out);
}

// Round 2
// 25.146 us; speedup vs baseline: 1.1035x; 1.1035x over previous
//
#include <hip/hip_runtime.h>
#include <math.h>

#define N_SIZE 4096
#define B_SIZE 8192
#define NH 2048            // j-half staged in LDS
#define T_PER_WAVE 2

typedef float v2f __attribute__((ext_vector_type(2)));

__device__ __forceinline__ float wave_sum(float v) {
#pragma unroll
    for (int off = 32; off >= 1; off >>= 1)
        v += __shfl_xor(v, off, 64);
    return v;
}

// packed tanh pieces: exp2/rcp are scalar trans ops, rest packs to v_pk_*
__device__ __forceinline__ v2f tanh2(v2f x) {
    v2f xe = x * 2.885390081777927f;                 // 2*log2(e)
    v2f ex;
    ex.x = __builtin_amdgcn_exp2f(xe.x);
    ex.y = __builtin_amdgcn_exp2f(xe.y);
    v2f d = ex + 1.0f;
    v2f r;
    r.x = __builtin_amdgcn_rcpf(d.x);
    r.y = __builtin_amdgcn_rcpf(d.y);
    return 1.0f - 2.0f * r;                          // exp2 inf -> r=0 -> 1; exp2 0 -> -1
}

__global__ __launch_bounds__(512, 4)
void bif_kernel(const float* __restrict__ k_t,
                const float* __restrict__ phase,
                const float* __restrict__ mono,
                const float* __restrict__ dKn,
                const float* __restrict__ amp_p,
                const float* __restrict__ w_p,
                const float* __restrict__ stim,
                const float* __restrict__ alpha,
                const float* __restrict__ Im,
                const float* __restrict__ mm,
                const float* __restrict__ nm,
                float* __restrict__ out) {
    __shared__ float s_m0[NH], s_m1[NH], s_n0[NH], s_n1[NH], s_I0[NH], s_cv[NH];

    const int lane = threadIdx.x & 63;
    const int wid  = threadIdx.x >> 6;               // 0..7
    const int b0   = (blockIdx.x * 8 + wid) * T_PER_WAVE;

    const float amp = amp_p[0];
    const float w   = w_p[0];
    const float st0 = stim[0];
    const float st1 = stim[1];
    const float tau_sw = w * 0.1f;
    const float phi0 = atanf(tau_sw);
    const float vamp = amp / sqrtf(1.0f + tau_sw * tau_sw);

    float k0[T_PER_WAVE], k1[T_PER_WAVE], vo[T_PER_WAVE], uo[T_PER_WAVE], ph[T_PER_WAVE];
#pragma unroll
    for (int t = 0; t < T_PER_WAVE; ++t) {
        int b = b0 + t;
        k0[t] = k_t[2 * b];
        k1[t] = k_t[2 * b + 1];
        float p = phase[b];
        ph[t] = p;
        vo[t] = vamp * sinf(p - phi0);
        uo[t] = amp * sinf(p);
    }

    v2f As0[T_PER_WAVE] = {}, As1[T_PER_WAVE] = {};
    v2f A00[T_PER_WAVE] = {}, A01[T_PER_WAVE] = {};
    v2f A10[T_PER_WAVE] = {}, A11[T_PER_WAVE] = {};

    for (int half = 0; half < 2; ++half) {
        // ---- stage 48KB into LDS (512 threads x 4 floats x 6 arrays) ----
        {
            const int t4 = threadIdx.x * 4;          // 0..2047
            const int g  = half * NH + t4;
            *(float4*)&s_m0[t4] = *(const float4*)&mm[g];
            *(float4*)&s_m1[t4] = *(const float4*)&mm[N_SIZE + g];
            *(float4*)&s_n0[t4] = *(const float4*)&nm[g];
            *(float4*)&s_n1[t4] = *(const float4*)&nm[N_SIZE + g];
            *(float4*)&s_I0[t4] = *(const float4*)&Im[g];
            float4 i1 = *(const float4*)&Im[N_SIZE + g];
            float4 i2 = *(const float4*)&Im[2 * N_SIZE + g];
            float4 cv;
            cv.x = st0 * i1.x + st1 * i2.x;
            cv.y = st0 * i1.y + st1 * i2.y;
            cv.z = st0 * i1.z + st1 * i2.z;
            cv.w = st0 * i1.w + st1 * i2.w;
            *(float4*)&s_cv[t4] = cv;
        }
        __syncthreads();

#pragma unroll 2
        for (int it = 0; it < NH / 256; ++it) {      // 8 iters per half
            const int j = it * 256 + lane * 4;
            float4 fm0 = *(const float4*)&s_m0[j];
            float4 fm1 = *(const float4*)&s_m1[j];
            float4 fn0 = *(const float4*)&s_n0[j];
            float4 fn1 = *(const float4*)&s_n1[j];
            float4 fi0 = *(const float4*)&s_I0[j];
            float4 fcv = *(const float4*)&s_cv[j];
            v2f Ms0[2] = {{fm0.x, fm0.y}, {fm0.z, fm0.w}};
            v2f Ms1[2] = {{fm1.x, fm1.y}, {fm1.z, fm1.w}};
            v2f Nn0[2] = {{fn0.x, fn0.y}, {fn0.z, fn0.w}};
            v2f Nn1[2] = {{fn1.x, fn1.y}, {fn1.z, fn1.w}};
            v2f Iv[2]  = {{fi0.x, fi0.y}, {fi0.z, fi0.w}};
            v2f Cv[2]  = {{fcv.x, fcv.y}, {fcv.z, fcv.w}};
#pragma unroll
            for (int p = 0; p < 2; ++p) {
#pragma unroll
                for (int t = 0; t < T_PER_WAVE; ++t) {
                    v2f x  = Cv[p] + k0[t] * Ms0[p] + k1[t] * Ms1[p] + vo[t] * Iv[p];
                    v2f tx = tanh2(x);
                    v2f dphi = 1.0f - tx * tx;
                    v2f a0 = dphi * Ms0[p];
                    v2f a1 = dphi * Ms1[p];
                    As0[t] += tx * Nn0[p];
                    As1[t] += tx * Nn1[p];
                    A00[t] += a0 * Nn0[p];
                    A01[t] += a0 * Nn1[p];
                    A10[t] += a1 * Nn0[p];
                    A11[t] += a1 * Nn1[p];
                }
            }
        }
        __syncthreads();                             // protect LDS before restage
    }

    // ---- reduce & write ----
    const float a00 = alpha[0], a01 = alpha[1], a02 = alpha[2];
    const float a10 = alpha[3], a11 = alpha[4], a12 = alpha[5];
    const float invN = 1.0f / 4096.0f;
    const float DT = 0.0005f;
#pragma unroll
    for (int t = 0; t < T_PER_WAVE; ++t) {
        float s0  = wave_sum(As0[t].x + As0[t].y);
        float s1  = wave_sum(As1[t].x + As1[t].y);
        float j00 = wave_sum(A00[t].x + A00[t].y);
        float j01 = wave_sum(A01[t].x + A01[t].y);
        float j10 = wave_sum(A10[t].x + A10[t].y);
        float j11 = wave_sum(A11[t].x + A11[t].y);
        if (lane == 0) {
            const int b = b0 + t;
            float ua0 = uo[t] * a00 + st0 * a01 + st1 * a02;
            float ua1 = uo[t] * a10 + st0 * a11 + st1 * a12;
            float dK0 = 10.0f * (-k0[t] + s0 * invN + ua0);
            float dK1 = 10.0f * (-k1[t] + s1 * invN + ua1);
            out[2 * b]     = fmaf(DT, dK0, k0[t]);
            out[2 * b + 1] = fmaf(DT, dK1, k1[t]);
            out[B_SIZE * 2 + b] = ph[t] + DT * w;
            float J00 = 10.0f * (j00 * invN - 1.0f);
            float J01 = 10.0f * (j01 * invN);
            float J10 = 10.0f * (j10 * invN);
            float J11 = 10.0f * (j11 * invN - 1.0f);
            float M00 = mono[4 * b], M01 = mono[4 * b + 1];
            float M10 = mono[4 * b + 2], M11 = mono[4 * b + 3];
            float* om = out + B_SIZE * 3 + 4 * b;
            om[0] = M00 + DT * (J00 * M00 + J01 * M10);
            om[1] = M01 + DT * (J00 * M01 + J01 * M11);
            om[2] = M10 + DT * (J10 * M00 + J11 * M10);
            om[3] = M11 + DT * (J10 * M01 + J11 * M11);
            out[B_SIZE * 7 + b] = dKn[b] + sqrtf(dK0 * dK0 + dK1 * dK1);
        }
    }
}

extern "C" void kernel_launch(void* const* d_in, const int* in_sizes, int n_in,
                              void* d_out, int out_size, void* d_ws, size_t ws_size,
                              hipStream_t stream) {
    const float* k_t   = (const float*)d_in[0];
    const float* phase = (const float*)d_in[1];
    const float* mono  = (const float*)d_in[2];
    const float* dKn   = (const float*)d_in[3];
    const float* amp   = (const float*)d_in[4];
    const float* w     = (const float*)d_in[5];
    const float* stim  = (const float*)d_in[6];
    const float* alpha = (const float*)d_in[7];
    const float* Im    = (const float*)d_in[8];
    const float* mm    = (const float*)d_in[9];
    const float* nm    = (const float*)d_in[10];
    float* out = (float*)d_out;

    // 8192 trials / (8 waves * 2 trials) = 512 blocks; 2 blocks/CU, 4 waves/SIMD
    bif_kernel<<<B_SIZE / (8 * T_PER_WAVE), 512, 0, stream>>>(
        k_t, phase, mono, dKn, amp, w, stim, alpha, Im, mm, nm, out);
}

// Round 3
// 24.732 us; speedup vs baseline: 1.1220x; 1.0167x over previous
//
#include <hip/hip_runtime.h>
#include <math.h>

#define N_SIZE 4096
#define B_SIZE 8192
#define T 4                     // trials per wave
#define NHALF 2048              // j elements per wave (half of N)

typedef float v2f __attribute__((ext_vector_type(2)));

__device__ __forceinline__ float wave_sum(float v) {
#pragma unroll
    for (int off = 32; off >= 1; off >>= 1)
        v += __shfl_xor(v, off, 64);
    return v;
}

// tanh(x) = 1 - 2/(exp2(2x*log2e)+1); exp2 overflow -> rcp(inf)=0 -> +1, underflow -> -1
__device__ __forceinline__ v2f tanh2(v2f x) {
    v2f xe = x * 2.885390081777927f;
    v2f ex;
    ex.x = __builtin_amdgcn_exp2f(xe.x);
    ex.y = __builtin_amdgcn_exp2f(xe.y);
    v2f d = ex + 1.0f;
    v2f r;
    r.x = __builtin_amdgcn_rcpf(d.x);
    r.y = __builtin_amdgcn_rcpf(d.y);
    return 1.0f - 2.0f * r;
}

__global__ __launch_bounds__(1024)
void bif_kernel(const float* __restrict__ k_t,
                const float* __restrict__ phase,
                const float* __restrict__ mono,
                const float* __restrict__ dKn,
                const float* __restrict__ amp_p,
                const float* __restrict__ w_p,
                const float* __restrict__ stim,
                const float* __restrict__ alpha,
                const float* __restrict__ Im,
                const float* __restrict__ mm,
                const float* __restrict__ nm,
                float* __restrict__ out) {
    __shared__ float s_m0[N_SIZE], s_m1[N_SIZE], s_n0[N_SIZE], s_n1[N_SIZE];
    __shared__ float s_I0[N_SIZE], s_cv[N_SIZE];
    __shared__ float s_red[8 * 2 * 6 * T];   // [group][half][acc][trial]

    const int tid  = threadIdx.x;
    const int lane = tid & 63;
    const int wvi  = tid >> 6;      // 0..15
    const int g    = wvi >> 1;      // 0..7 trial group
    const int h    = wvi & 1;       // j-half
    const int b0   = blockIdx.x * 32 + g * T;

    const float st0 = stim[0];
    const float st1 = stim[1];

    // ---- stage all 96KB once: 1024 threads x 4 floats per array ----
    {
        const int t4 = tid * 4;
        *(float4*)&s_m0[t4] = *(const float4*)&mm[t4];
        *(float4*)&s_m1[t4] = *(const float4*)&mm[N_SIZE + t4];
        *(float4*)&s_n0[t4] = *(const float4*)&nm[t4];
        *(float4*)&s_n1[t4] = *(const float4*)&nm[N_SIZE + t4];
        *(float4*)&s_I0[t4] = *(const float4*)&Im[t4];
        float4 i1 = *(const float4*)&Im[N_SIZE + t4];
        float4 i2 = *(const float4*)&Im[2 * N_SIZE + t4];
        float4 cv;
        cv.x = st0 * i1.x + st1 * i2.x;
        cv.y = st0 * i1.y + st1 * i2.y;
        cv.z = st0 * i1.z + st1 * i2.z;
        cv.w = st0 * i1.w + st1 * i2.w;
        *(float4*)&s_cv[t4] = cv;
    }

    // ---- per-trial params (uniform across lanes) ----
    const float amp = amp_p[0];
    const float w   = w_p[0];
    const float tau_sw = w * 0.1f;
    const float phi0 = atanf(tau_sw);
    const float vamp = amp / sqrtf(1.0f + tau_sw * tau_sw);

    float k0[T], k1[T], vo[T];
#pragma unroll
    for (int t = 0; t < T; ++t) {
        const int b = b0 + t;
        k0[t] = k_t[2 * b];
        k1[t] = k_t[2 * b + 1];
        vo[t] = vamp * sinf(phase[b] - phi0);
    }

    __syncthreads();

    v2f As0[T] = {}, As1[T] = {};
    v2f A00[T] = {}, A01[T] = {};
    v2f A10[T] = {}, A11[T] = {};

    const int base = h * NHALF;
#pragma unroll 2
    for (int it = 0; it < NHALF / 256; ++it) {      // 8 iterations
        const int j = base + it * 256 + lane * 4;
        float4 fm0 = *(const float4*)&s_m0[j];
        float4 fm1 = *(const float4*)&s_m1[j];
        float4 fn0 = *(const float4*)&s_n0[j];
        float4 fn1 = *(const float4*)&s_n1[j];
        float4 fi0 = *(const float4*)&s_I0[j];
        float4 fcv = *(const float4*)&s_cv[j];
        v2f Ms0[2] = {{fm0.x, fm0.y}, {fm0.z, fm0.w}};
        v2f Ms1[2] = {{fm1.x, fm1.y}, {fm1.z, fm1.w}};
        v2f Nn0[2] = {{fn0.x, fn0.y}, {fn0.z, fn0.w}};
        v2f Nn1[2] = {{fn1.x, fn1.y}, {fn1.z, fn1.w}};
        v2f Iv[2]  = {{fi0.x, fi0.y}, {fi0.z, fi0.w}};
        v2f Cv[2]  = {{fcv.x, fcv.y}, {fcv.z, fcv.w}};
#pragma unroll
        for (int p = 0; p < 2; ++p) {
#pragma unroll
            for (int t = 0; t < T; ++t) {
                v2f x  = Cv[p] + k0[t] * Ms0[p] + k1[t] * Ms1[p] + vo[t] * Iv[p];
                v2f tx = tanh2(x);
                v2f dphi = 1.0f - tx * tx;
                v2f a0 = dphi * Ms0[p];
                v2f a1 = dphi * Ms1[p];
                As0[t] += tx * Nn0[p];
                As1[t] += tx * Nn1[p];
                A00[t] += a0 * Nn0[p];
                A01[t] += a0 * Nn1[p];
                A10[t] += a1 * Nn0[p];
                A11[t] += a1 * Nn1[p];
            }
        }
    }

    // ---- in-wave reduce, publish partials ----
#pragma unroll
    for (int t = 0; t < T; ++t) {
        float r0 = wave_sum(As0[t].x + As0[t].y);
        float r1 = wave_sum(As1[t].x + As1[t].y);
        float r2 = wave_sum(A00[t].x + A00[t].y);
        float r3 = wave_sum(A01[t].x + A01[t].y);
        float r4 = wave_sum(A10[t].x + A10[t].y);
        float r5 = wave_sum(A11[t].x + A11[t].y);
        if (lane == 0) {
            float* rp = &s_red[((g * 2 + h) * 6) * T + t];
            rp[0 * T] = r0; rp[1 * T] = r1; rp[2 * T] = r2;
            rp[3 * T] = r3; rp[4 * T] = r4; rp[5 * T] = r5;
        }
    }
    __syncthreads();

    // ---- epilogue: lanes 0..3 of each h==0 wave, one trial each ----
    if (h == 0 && lane < T) {
        const int t = lane;
        const int b = b0 + t;
        const float* r0p = &s_red[((g * 2 + 0) * 6) * T + t];
        const float* r1p = &s_red[((g * 2 + 1) * 6) * T + t];
        float s0  = r0p[0 * T] + r1p[0 * T];
        float s1  = r0p[1 * T] + r1p[1 * T];
        float j00 = r0p[2 * T] + r1p[2 * T];
        float j01 = r0p[3 * T] + r1p[3 * T];
        float j10 = r0p[4 * T] + r1p[4 * T];
        float j11 = r0p[5 * T] + r1p[5 * T];

        const float kk0 = k_t[2 * b];
        const float kk1 = k_t[2 * b + 1];
        const float p   = phase[b];
        const float uo  = amp * sinf(p);
        const float a00 = alpha[0], a01 = alpha[1], a02 = alpha[2];
        const float a10 = alpha[3], a11 = alpha[4], a12 = alpha[5];
        const float invN = 1.0f / 4096.0f;
        const float DT = 0.0005f;

        float ua0 = uo * a00 + st0 * a01 + st1 * a02;
        float ua1 = uo * a10 + st0 * a11 + st1 * a12;
        float dK0 = 10.0f * (-kk0 + s0 * invN + ua0);
        float dK1 = 10.0f * (-kk1 + s1 * invN + ua1);
        out[2 * b]     = fmaf(DT, dK0, kk0);
        out[2 * b + 1] = fmaf(DT, dK1, kk1);
        out[B_SIZE * 2 + b] = p + DT * w;
        float J00 = 10.0f * (j00 * invN - 1.0f);
        float J01 = 10.0f * (j01 * invN);
        float J10 = 10.0f * (j10 * invN);
        float J11 = 10.0f * (j11 * invN - 1.0f);
        float M00 = mono[4 * b], M01 = mono[4 * b + 1];
        float M10 = mono[4 * b + 2], M11 = mono[4 * b + 3];
        float* om = out + B_SIZE * 3 + 4 * b;
        om[0] = M00 + DT * (J00 * M00 + J01 * M10);
        om[1] = M01 + DT * (J00 * M01 + J01 * M11);
        om[2] = M10 + DT * (J10 * M00 + J11 * M10);
        om[3] = M11 + DT * (J10 * M01 + J11 * M11);
        out[B_SIZE * 7 + b] = dKn[b] + sqrtf(dK0 * dK0 + dK1 * dK1);
    }
}

extern "C" void kernel_launch(void* const* d_in, const int* in_sizes, int n_in,
                              void* d_out, int out_size, void* d_ws, size_t ws_size,
                              hipStream_t stream) {
    const float* k_t   = (const float*)d_in[0];
    const float* phase = (const float*)d_in[1];
    const float* mono  = (const float*)d_in[2];
    const float* dKn   = (const float*)d_in[3];
    const float* amp   = (const float*)d_in[4];
    const float* w     = (const float*)d_in[5];
    const float* stim  = (const float*)d_in[6];
    const float* alpha = (const float*)d_in[7];
    const float* Im    = (const float*)d_in[8];
    const float* mm    = (const float*)d_in[9];
    const float* nm    = (const float*)d_in[10];
    float* out = (float*)d_out;

    // 256 blocks x 1024 threads: 1 block/CU, 16 waves/CU, 32 trials/block
    bif_kernel<<<B_SIZE / 32, 1024, 0, stream>>>(
        k_t, phase, mono, dKn, amp, w, stim, alpha, Im, mm, nm, out);
}